// Round 6
// baseline (682.198 us; speedup 1.0000x reference)
//
#include <hip/hip_runtime.h>
#include <hip/hip_fp16.h>

typedef _Float16 f16;
typedef f16 f16x8 __attribute__((ext_vector_type(8)));
typedef f16 f16x4 __attribute__((ext_vector_type(4)));
typedef f16 f16x2 __attribute__((ext_vector_type(2)));
typedef float f32x4 __attribute__((ext_vector_type(4)));

#define DM 128
#define DFF 512

// Packed split-f16 weight images: 4 mats (W1a,W2a,W1b,W2b) x 2 planes (hi,lo),
// 65536 f16 per plane = 1 MiB total. Static device memory; rewritten
// deterministically by prep_weights on every kernel_launch call.
// f16-unit strides: mat 131072, plane 65536.
__device__ __align__(16) f16 g_wimg[524288];

// Byte offset of f16 element (row, k) in a swizzled [64][128] f16 LDS plane.
// XOR on byte-bits 4-6 breaks the stride-256B bank alias (guide §6 G4);
// bijective within each row, preserves 8B/16B block contiguity.
__device__ __forceinline__ int swz(int row, int k2 /* = 2*k bytes */) {
  return row * 256 + (k2 ^ ((row & 7) << 4));
}

// gelu(x) = 0.5 x (1 + erf(x/sqrt2)); erf via Abramowitz-Stegun 7.1.26 (|err|<1.5e-7)
__device__ __forceinline__ float gelu_f(float x) {
  float z = fabsf(x) * 0.70710678118654752f;
  float t = __builtin_amdgcn_rcpf(fmaf(0.3275911f, z, 1.0f));
  float p = fmaf(1.061405429f, t, -1.453152027f);
  p = fmaf(p, t, 1.421413741f);
  p = fmaf(p, t, -0.284496736f);
  p = fmaf(p, t, 0.254829592f);
  p = p * t;
  float e = __expf(-z * z);
  float er = fmaf(-p, e, 1.0f);
  er = copysignf(er, x);
  return 0.5f * x * (1.0f + er);
}

// ---------------------------------------------------------------------------
// Fragment-major weight image (per plane):
//   frag = ((chunk*8 + cb)*4 + ks); byte = frag*1024 + lane*16 + j*2
//   element (lane, j) = B[k = ks*32 + (lane>>4)*8 + j][col = cb*16 + (lane&15)]
//   type1 (W1*): [128][512] row-major, col_global = chunk*128 + col
//   type2 (W2*): [512][128] row-major, k_global  = chunk*128 + k
// plane 0 = (f16)w ; plane 1 = (f16)(w - (float)(f16)w)  [split-f16 lo part]
// ---------------------------------------------------------------------------
__global__ __launch_bounds__(256) void prep_weights(
    const float* __restrict__ W1a, const float* __restrict__ W2a,
    const float* __restrict__ W1b, const float* __restrict__ W2b) {
  int p = blockIdx.x * 256 + threadIdx.x;  // pair index, 262144 total
  int mat = p >> 16;
  int rem = p & 65535;
  int plane = rem >> 15;
  int rem2 = rem & 32767;
  int frag = rem2 >> 8;  // 128 frags per plane
  int q = rem2 & 255;
  int lane = q >> 2;
  int j = (q & 3) * 2;
  int chunk = frag >> 5;
  int cb = (frag >> 2) & 7;
  int ks = frag & 3;
  int l15 = lane & 15, l4 = lane >> 4;
  int col16 = cb * 16 + l15;
  int kk = ks * 32 + l4 * 8 + j;
  const float* W = (mat == 0) ? W1a : (mat == 1) ? W2a : (mat == 2) ? W1b : W2b;
  float s0, s1;
  if ((mat & 1) == 0) {  // type1: [128][512]
    int colg = chunk * 128 + col16;
    s0 = W[kk * 512 + colg];
    s1 = W[(kk + 1) * 512 + colg];
  } else {               // type2: [512][128]
    int kg = chunk * 128 + kk;
    s0 = W[kg * 128 + col16];
    s1 = W[(kg + 1) * 128 + col16];
  }
  f16x2 h;
  if (plane == 0) {
    h.x = (f16)s0;
    h.y = (f16)s1;
  } else {
    h.x = (f16)(s0 - (float)(f16)s0);
    h.y = (f16)(s1 - (float)(f16)s1);
  }
  *(f16x2*)((unsigned char*)g_wimg + mat * 262144 + plane * 131072 +
            frag * 1024 + lane * 16 + j * 2) = h;
}

// One MLP (x@W1+b1 -> gelu -> @W2), split-f16: product reconstructed as
// Ahi*Bhi + Alo*Bhi + Ahi*Blo (residual AloBlo ~2^-24, negligible).
// zacc enters holding the f32 residual and accumulates GEMM2.
__device__ __forceinline__ void run_mlp(
    const f16x8 (&afh)[2][4], const f16x8 (&afl)[2][4], f32x4 (&zacc)[2][4],
    const f16* __restrict__ Wimg1, const f16* __restrict__ Wimg2,
    const float* __restrict__ b1,
    unsigned char* shh, unsigned char* shl,
    int wr, int wc, int l15, int l4, int lane) {
  for (int chunk = 0; chunk < 4; ++chunk) {
    // ---- GEMM1: t = w @ W1[:, chunk] (A from regs, B from global/L2) ----
    const f16* b1h = Wimg1 + chunk * 16384;
    const f16* b1l = Wimg1 + 65536 + chunk * 16384;
    f32x4 t[2][4];
#pragma unroll
    for (int ri = 0; ri < 2; ++ri)
#pragma unroll
      for (int ci = 0; ci < 4; ++ci) t[ri][ci] = (f32x4){0.f, 0.f, 0.f, 0.f};
#pragma unroll
    for (int ks = 0; ks < 4; ++ks) {
#pragma unroll
      for (int ci = 0; ci < 4; ++ci) {
        int cb = wc * 4 + ci;
        const int fo = ((cb * 4 + ks) * 64 + lane) * 8;
        f16x8 bh = *(const f16x8*)(b1h + fo);
        f16x8 bl = *(const f16x8*)(b1l + fo);
        t[0][ci] = __builtin_amdgcn_mfma_f32_16x16x32_f16(afh[0][ks], bh, t[0][ci], 0, 0, 0);
        t[1][ci] = __builtin_amdgcn_mfma_f32_16x16x32_f16(afh[1][ks], bh, t[1][ci], 0, 0, 0);
        t[0][ci] = __builtin_amdgcn_mfma_f32_16x16x32_f16(afl[0][ks], bh, t[0][ci], 0, 0, 0);
        t[1][ci] = __builtin_amdgcn_mfma_f32_16x16x32_f16(afl[1][ks], bh, t[1][ci], 0, 0, 0);
        t[0][ci] = __builtin_amdgcn_mfma_f32_16x16x32_f16(afh[0][ks], bl, t[0][ci], 0, 0, 0);
        t[1][ci] = __builtin_amdgcn_mfma_f32_16x16x32_f16(afh[1][ks], bl, t[1][ci], 0, 0, 0);
      }
    }
    __syncthreads();  // prior readers of shh/shl (prev GEMM2 / af loads) are done
    // ---- bias + GELU -> h (split f16, swizzled LDS planes) ----
#pragma unroll
    for (int ci = 0; ci < 4; ++ci) {
      int cl = wc * 64 + ci * 16 + l15;
      float bias = b1[chunk * 128 + cl];
#pragma unroll
      for (int ri = 0; ri < 2; ++ri)
#pragma unroll
        for (int r = 0; r < 4; ++r) {
          int row = 32 * wr + 16 * ri + l4 * 4 + r;
          float g = gelu_f(t[ri][ci][r] + bias);
          f16 gh = (f16)g;
          *(f16*)(shh + swz(row, 2 * cl)) = gh;
          *(f16*)(shl + swz(row, 2 * cl)) = (f16)(g - (float)gh);
        }
    }
    __syncthreads();  // h visible
    // ---- GEMM2: zacc += h @ W2[chunk, :] ----
    const f16* b2h = Wimg2 + chunk * 16384;
    const f16* b2l = Wimg2 + 65536 + chunk * 16384;
    f16x8 a2h[2][4], a2l[2][4];
#pragma unroll
    for (int ri = 0; ri < 2; ++ri)
#pragma unroll
      for (int ks = 0; ks < 4; ++ks) {
        int row = 32 * wr + 16 * ri + l15;
        int off = swz(row, 2 * (ks * 32 + l4 * 8));
        a2h[ri][ks] = *(const f16x8*)(shh + off);
        a2l[ri][ks] = *(const f16x8*)(shl + off);
      }
#pragma unroll
    for (int ks = 0; ks < 4; ++ks) {
#pragma unroll
      for (int ci = 0; ci < 4; ++ci) {
        int cb = wc * 4 + ci;
        const int fo = ((cb * 4 + ks) * 64 + lane) * 8;
        f16x8 bh = *(const f16x8*)(b2h + fo);
        f16x8 bl = *(const f16x8*)(b2l + fo);
        zacc[0][ci] = __builtin_amdgcn_mfma_f32_16x16x32_f16(a2h[0][ks], bh, zacc[0][ci], 0, 0, 0);
        zacc[1][ci] = __builtin_amdgcn_mfma_f32_16x16x32_f16(a2h[1][ks], bh, zacc[1][ci], 0, 0, 0);
        zacc[0][ci] = __builtin_amdgcn_mfma_f32_16x16x32_f16(a2l[0][ks], bh, zacc[0][ci], 0, 0, 0);
        zacc[1][ci] = __builtin_amdgcn_mfma_f32_16x16x32_f16(a2l[1][ks], bh, zacc[1][ci], 0, 0, 0);
        zacc[0][ci] = __builtin_amdgcn_mfma_f32_16x16x32_f16(a2h[0][ks], bl, zacc[0][ci], 0, 0, 0);
        zacc[1][ci] = __builtin_amdgcn_mfma_f32_16x16x32_f16(a2h[1][ks], bl, zacc[1][ci], 0, 0, 0);
      }
    }
  }
}

__global__ __launch_bounds__(256) void tsal_kernel(
    const float* __restrict__ x,
    const float* __restrict__ bo_time, const float* __restrict__ bo_recv,
    const float* __restrict__ g1, const float* __restrict__ be1,
    const float* __restrict__ g2, const float* __restrict__ be2,
    const float* __restrict__ g3, const float* __restrict__ be3,
    const float* __restrict__ g4, const float* __restrict__ be4,
    const float* __restrict__ b1a, const float* __restrict__ b2a,
    const float* __restrict__ b1b, const float* __restrict__ b2b,
    float* __restrict__ out) {
  __shared__ __align__(16) unsigned char smem[34816];
  unsigned char* shh = smem;             // [64][128] f16 swizzled, hi plane
  unsigned char* shl = smem + 16384;     // [64][128] f16 swizzled, lo plane
  float2* red1 = (float2*)(smem + 32768);  // [64][2] partial {sum, sumsq}
  float2* red2 = (float2*)(smem + 33792);

  const int tid = threadIdx.x;
  const int lane = tid & 63;
  const int wv = tid >> 6;
  const int wr = wv >> 1, wc = wv & 1;   // 2x2 wave grid: 32-row x 64-col tiles
  const int l15 = lane & 15, l4 = lane >> 4;
  const int row0 = blockIdx.x * 64;

  // ---------------- Phase 0: LN1(x + bo_time) -> split-f16 LDS planes ----------------
#pragma unroll
  for (int it = 0; it < 8; ++it) {
    int rl = wv * 16 + it * 2 + (lane >> 5);
    int c0 = (lane & 31) * 4;
    float4 xv = *(const float4*)(x + (size_t)(row0 + rl) * 128 + c0);
    float4 bt = *(const float4*)(bo_time + c0);
    float vx = xv.x + bt.x, vy = xv.y + bt.y, vz = xv.z + bt.z, vw = xv.w + bt.w;
    float s = vx + vy + vz + vw;
    float q = vx * vx + vy * vy + vz * vz + vw * vw;
#pragma unroll
    for (int m = 16; m >= 1; m >>= 1) {
      s += __shfl_xor(s, m, 64);
      q += __shfl_xor(q, m, 64);
    }
    float mm = s * (1.f / 128.f);
    float rs = rsqrtf(q * (1.f / 128.f) - mm * mm + 1e-5f);
    float4 gv = *(const float4*)(g1 + c0);
    float4 bv = *(const float4*)(be1 + c0);
    float w0 = (vx - mm) * rs * gv.x + bv.x;
    float w1 = (vy - mm) * rs * gv.y + bv.y;
    float w2 = (vz - mm) * rs * gv.z + bv.z;
    float w3 = (vw - mm) * rs * gv.w + bv.w;
    int off = rl * 256 + ((c0 * 2) ^ ((rl & 7) << 4));
    f16x4 hv, lv;
    hv.x = (f16)w0; hv.y = (f16)w1; hv.z = (f16)w2; hv.w = (f16)w3;
    lv.x = (f16)(w0 - (float)hv.x);
    lv.y = (f16)(w1 - (float)hv.y);
    lv.z = (f16)(w2 - (float)hv.z);
    lv.w = (f16)(w3 - (float)hv.w);
    *(f16x4*)(shh + off) = hv;
    *(f16x4*)(shl + off) = lv;
  }
  __syncthreads();

  // ---- A-fragments of w (held in regs all of stage A) ----
  f16x8 afh[2][4], afl[2][4];
#pragma unroll
  for (int ri = 0; ri < 2; ++ri)
#pragma unroll
    for (int ks = 0; ks < 4; ++ks) {
      int row = 32 * wr + 16 * ri + l15;
      int off = swz(row, 2 * (ks * 32 + l4 * 8));
      afh[ri][ks] = *(const f16x8*)(shh + off);
      afl[ri][ks] = *(const f16x8*)(shl + off);
    }
  // ---- residual w into zacc (C/D-layout scalar reads; w = hi+lo exact to 2^-24) ----
  f32x4 zacc[2][4];
#pragma unroll
  for (int ri = 0; ri < 2; ++ri)
#pragma unroll
    for (int ci = 0; ci < 4; ++ci)
#pragma unroll
      for (int r = 0; r < 4; ++r) {
        int row = 32 * wr + 16 * ri + l4 * 4 + r;
        int col = wc * 64 + ci * 16 + l15;
        int off = swz(row, 2 * col);
        zacc[ri][ci][r] = (float)(*(const f16*)(shh + off)) +
                          (float)(*(const f16*)(shl + off));
      }

  // ---------------- Stage A: z_pre = w + MLP1(w) ----------------
  run_mlp(afh, afl, zacc, g_wimg, g_wimg + 131072, b1a, shh, shl, wr, wc, l15, l4, lane);

  // + b2a
#pragma unroll
  for (int ci = 0; ci < 4; ++ci) {
    float bb = b2a[wc * 64 + ci * 16 + l15];
#pragma unroll
    for (int ri = 0; ri < 2; ++ri)
#pragma unroll
      for (int r = 0; r < 4; ++r) zacc[ri][ci][r] += bb;
  }
  // LN2 partials (row split across wc halves -> LDS combine)
#pragma unroll
  for (int ri = 0; ri < 2; ++ri)
#pragma unroll
    for (int r = 0; r < 4; ++r) {
      float s = 0.f, q = 0.f;
#pragma unroll
      for (int ci = 0; ci < 4; ++ci) {
        float v = zacc[ri][ci][r];
        s += v; q += v * v;
      }
#pragma unroll
      for (int m = 8; m >= 1; m >>= 1) {
        s += __shfl_xor(s, m, 64);
        q += __shfl_xor(q, m, 64);
      }
      if (l15 == 0) red1[(32 * wr + 16 * ri + l4 * 4 + r) * 2 + wc] = make_float2(s, q);
    }
  __syncthreads();
  // LN2 apply, + bo_recv, LN3 partials
  float g2v[4], be2v[4], brv[4];
#pragma unroll
  for (int ci = 0; ci < 4; ++ci) {
    int col = wc * 64 + ci * 16 + l15;
    g2v[ci] = g2[col]; be2v[ci] = be2[col]; brv[ci] = bo_recv[col];
  }
#pragma unroll
  for (int ri = 0; ri < 2; ++ri)
#pragma unroll
    for (int r = 0; r < 4; ++r) {
      int row = 32 * wr + 16 * ri + l4 * 4 + r;
      float2 pa = red1[row * 2 + 0], pb = red1[row * 2 + 1];
      float mm = (pa.x + pb.x) * (1.f / 128.f);
      float var = (pa.y + pb.y) * (1.f / 128.f) - mm * mm;
      float rs = rsqrtf(var + 1e-5f);
      float s = 0.f, q = 0.f;
#pragma unroll
      for (int ci = 0; ci < 4; ++ci) {
        float zn = (zacc[ri][ci][r] - mm) * rs * g2v[ci] + be2v[ci];
        float t3 = zn + brv[ci];
        zacc[ri][ci][r] = t3;
        s += t3; q += t3 * t3;
      }
#pragma unroll
      for (int m = 8; m >= 1; m >>= 1) {
        s += __shfl_xor(s, m, 64);
        q += __shfl_xor(q, m, 64);
      }
      if (l15 == 0) red2[row * 2 + wc] = make_float2(s, q);
    }
  __syncthreads();
  // LN3 -> y: write split y to LDS planes; keep f32 y in zacc as stage-B residual
  float g3v[4], be3v[4];
#pragma unroll
  for (int ci = 0; ci < 4; ++ci) {
    int col = wc * 64 + ci * 16 + l15;
    g3v[ci] = g3[col]; be3v[ci] = be3[col];
  }
#pragma unroll
  for (int ri = 0; ri < 2; ++ri)
#pragma unroll
    for (int r = 0; r < 4; ++r) {
      int row = 32 * wr + 16 * ri + l4 * 4 + r;
      float2 pa = red2[row * 2 + 0], pb = red2[row * 2 + 1];
      float mm = (pa.x + pb.x) * (1.f / 128.f);
      float var = (pa.y + pb.y) * (1.f / 128.f) - mm * mm;
      float rs = rsqrtf(var + 1e-5f);
#pragma unroll
      for (int ci = 0; ci < 4; ++ci) {
        int col = wc * 64 + ci * 16 + l15;
        float y = (zacc[ri][ci][r] - mm) * rs * g3v[ci] + be3v[ci];
        zacc[ri][ci][r] = y;
        f16 yh = (f16)y;
        *(f16*)(shh + swz(row, 2 * col)) = yh;
        *(f16*)(shl + swz(row, 2 * col)) = (f16)(y - (float)yh);
      }
    }
  __syncthreads();
  // reload A-fragments (now y); run_mlp's first barrier orders vs overwrites
#pragma unroll
  for (int ri = 0; ri < 2; ++ri)
#pragma unroll
    for (int ks = 0; ks < 4; ++ks) {
      int row = 32 * wr + 16 * ri + l15;
      int off = swz(row, 2 * (ks * 32 + l4 * 8));
      afh[ri][ks] = *(const f16x8*)(shh + off);
      afl[ri][ks] = *(const f16x8*)(shl + off);
    }

  // ---------------- Stage B: o_pre = y + MLP2(y) ----------------
  run_mlp(afh, afl, zacc, g_wimg + 262144, g_wimg + 393216, b1b, shh, shl, wr, wc, l15, l4, lane);

  // + b2b, LN4 partials
#pragma unroll
  for (int ci = 0; ci < 4; ++ci) {
    float bb = b2b[wc * 64 + ci * 16 + l15];
#pragma unroll
    for (int ri = 0; ri < 2; ++ri)
#pragma unroll
      for (int r = 0; r < 4; ++r) zacc[ri][ci][r] += bb;
  }
#pragma unroll
  for (int ri = 0; ri < 2; ++ri)
#pragma unroll
    for (int r = 0; r < 4; ++r) {
      float s = 0.f, q = 0.f;
#pragma unroll
      for (int ci = 0; ci < 4; ++ci) {
        float v = zacc[ri][ci][r];
        s += v; q += v * v;
      }
#pragma unroll
      for (int m = 8; m >= 1; m >>= 1) {
        s += __shfl_xor(s, m, 64);
        q += __shfl_xor(q, m, 64);
      }
      if (l15 == 0) red1[(32 * wr + 16 * ri + l4 * 4 + r) * 2 + wc] = make_float2(s, q);
    }
  __syncthreads();
  // LN4 -> output
  float g4v[4], be4v[4];
#pragma unroll
  for (int ci = 0; ci < 4; ++ci) {
    int col = wc * 64 + ci * 16 + l15;
    g4v[ci] = g4[col]; be4v[ci] = be4[col];
  }
#pragma unroll
  for (int ri = 0; ri < 2; ++ri)
#pragma unroll
    for (int r = 0; r < 4; ++r) {
      int row = 32 * wr + 16 * ri + l4 * 4 + r;
      float2 pa = red1[row * 2 + 0], pb = red1[row * 2 + 1];
      float mm = (pa.x + pb.x) * (1.f / 128.f);
      float var = (pa.y + pb.y) * (1.f / 128.f) - mm * mm;
      float rs = rsqrtf(var + 1e-5f);
#pragma unroll
      for (int ci = 0; ci < 4; ++ci) {
        int col = wc * 64 + ci * 16 + l15;
        float o = (zacc[ri][ci][r] - mm) * rs * g4v[ci] + be4v[ci];
        out[(size_t)(row0 + row) * 128 + col] = o;
      }
    }
}

extern "C" void kernel_launch(void* const* d_in, const int* in_sizes, int n_in,
                              void* d_out, int out_size, void* d_ws, size_t ws_size,
                              hipStream_t stream) {
  const float* x = (const float*)d_in[0];
  // d_in[1] = router (dead), d_in[3] = bo_send (dead)
  const float* bo_time = (const float*)d_in[2];
  const float* bo_recv = (const float*)d_in[4];
  const float* g1 = (const float*)d_in[5];
  const float* be1 = (const float*)d_in[6];
  const float* g2 = (const float*)d_in[7];
  const float* be2 = (const float*)d_in[8];
  const float* g3 = (const float*)d_in[9];
  const float* be3 = (const float*)d_in[10];
  const float* g4 = (const float*)d_in[11];
  const float* be4 = (const float*)d_in[12];
  const float* W1a = (const float*)d_in[13];
  const float* b1a = (const float*)d_in[14];
  const float* W2a = (const float*)d_in[15];
  const float* b2a = (const float*)d_in[16];
  const float* W1b = (const float*)d_in[17];
  const float* b1b = (const float*)d_in[18];
  const float* W2b = (const float*)d_in[19];
  const float* b2b = (const float*)d_in[20];
  float* outp = (float*)d_out;

  int nrows = in_sizes[0] / 128;  // 131072
  prep_weights<<<1024, 256, 0, stream>>>(W1a, W2a, W1b, W2b);
  tsal_kernel<<<nrows / 64, 256, 0, stream>>>(
      x, bo_time, bo_recv, g1, be1, g2, be2, g3, be3, g4, be4,
      b1a, b2a, b1b, b2b, outp);
}

// Round 8
// 654.687 us; speedup vs baseline: 1.0420x; 1.0420x over previous
//
#include <hip/hip_runtime.h>
#include <hip/hip_fp16.h>

typedef _Float16 f16;
typedef f16 f16x8 __attribute__((ext_vector_type(8)));
typedef f16 f16x2 __attribute__((ext_vector_type(2)));
typedef float f32x4 __attribute__((ext_vector_type(4)));

// Packed split-f16 weight images: 4 mats (W1a,W2a,W1b,W2b) x 2 planes (hi,lo),
// 65536 f16 per plane = 1 MiB. Layout + content VERIFIED by the R6 pass.
// f16-unit strides: mat 131072, plane 65536, frag 512, lane 8.
__device__ __align__(16) f16 g_wimg[524288];

// Per-wave f32 scratch row stride: 132 floats (128 + 4 pad) = 528 bytes.
// Pad rotates banks by 4/row (no XOR swizzle anywhere - correctness first).
#define RSTRIDE 528

// gelu(x) = 0.5 x (1 + erf(x/sqrt2)); erf via Abramowitz-Stegun 7.1.26 (|err|<1.5e-7)
__device__ __forceinline__ float gelu_f(float x) {
  float z = fabsf(x) * 0.70710678118654752f;
  float t = __builtin_amdgcn_rcpf(fmaf(0.3275911f, z, 1.0f));
  float p = fmaf(1.061405429f, t, -1.453152027f);
  p = fmaf(p, t, 1.421413741f);
  p = fmaf(p, t, -0.284496736f);
  p = fmaf(p, t, 0.254829592f);
  p = p * t;
  float e = __expf(-z * z);
  float er = fmaf(-p, e, 1.0f);
  er = copysignf(er, x);
  return 0.5f * x * (1.0f + er);
}

// ---------------------------------------------------------------------------
// prep_weights: byte-identical to the R6 PASSING kernel (HW-verified layout).
//   frag = ((chunk*8 + cb)*4 + ks); byte = frag*1024 + lane*16 + j*2
//   element (lane, j) = B[k = ks*32 + (lane>>4)*8 + j][col = cb*16 + (lane&15)]
//   type1 (W1*): col_global = chunk*128 + col   (512-dim chunked)
//   type2 (W2*): k_global  = chunk*128 + k      (512-dim chunked)
// The B-frag image of W1 is identically the A-frag image of W1^T (same lane
// conventions), reused for the swapped GEMM1.
// ---------------------------------------------------------------------------
__global__ __launch_bounds__(256) void prep_weights(
    const float* __restrict__ W1a, const float* __restrict__ W2a,
    const float* __restrict__ W1b, const float* __restrict__ W2b) {
  int p = blockIdx.x * 256 + threadIdx.x;  // pair index, 262144 total
  int mat = p >> 16;
  int rem = p & 65535;
  int plane = rem >> 15;
  int rem2 = rem & 32767;
  int frag = rem2 >> 8;
  int q = rem2 & 255;
  int lane = q >> 2;
  int j = (q & 3) * 2;
  int chunk = frag >> 5;
  int cb = (frag >> 2) & 7;
  int ks = frag & 3;
  int l15 = lane & 15, l4 = lane >> 4;
  int col16 = cb * 16 + l15;
  int kk = ks * 32 + l4 * 8 + j;
  const float* W = (mat == 0) ? W1a : (mat == 1) ? W2a : (mat == 2) ? W1b : W2b;
  float s0, s1;
  if ((mat & 1) == 0) {
    int colg = chunk * 128 + col16;
    s0 = W[kk * 512 + colg];
    s1 = W[(kk + 1) * 512 + colg];
  } else {
    int kg = chunk * 128 + kk;
    s0 = W[kg * 128 + col16];
    s1 = W[(kg + 1) * 128 + col16];
  }
  f16x2 h;
  if (plane == 0) {
    h.x = (f16)s0;
    h.y = (f16)s1;
  } else {
    h.x = (f16)(s0 - (float)(f16)s0);
    h.y = (f16)(s1 - (float)(f16)s1);
  }
  *(f16x2*)((unsigned char*)g_wimg + mat * 262144 + plane * 131072 +
            frag * 1024 + lane * 16 + j * 2) = h;
}

// Split 8 f32 into hi/lo f16x8 fragments (error-free to 2^-24).
__device__ __forceinline__ void split8(const float4& a, const float4& b,
                                       f16x8& h, f16x8& l) {
  float v[8] = {a.x, a.y, a.z, a.w, b.x, b.y, b.z, b.w};
#pragma unroll
  for (int j = 0; j < 8; ++j) {
    f16 x = (f16)v[j];
    h[j] = x;
    l[j] = (f16)(v[j] - (float)x);
  }
}

// One MLP stage, fully wave-local, barrier-free. scr = this wave's private
// [16][132] f32 scratch. bfh/bfl: activation frags (B-operand, x^T), in regs.
// zacc[n]: C/D accumulator (row = l4*4+r, col = n*16+l15), enters = residual.
// 3-term split: hi*hi + lo*hi + hi*lo (dropped lo*lo ~ 2^-24 relative).
__device__ __forceinline__ void mlp_stage(
    char* scr, const f16x8 (&bfh)[4], const f16x8 (&bfl)[4], f32x4 (&zacc)[8],
    const f16* __restrict__ W1img, const f16* __restrict__ W2img,
    const float* __restrict__ b1, int lane, int l15, int l4) {
  for (int chunk = 0; chunk < 4; ++chunk) {
    // ---- GEMM1 (swapped): t^T = W1^T-tile (A) x act^T (B) ----
#pragma unroll
    for (int m = 0; m < 8; ++m) {
      f32x4 t4 = {0.f, 0.f, 0.f, 0.f};
#pragma unroll
      for (int ks = 0; ks < 4; ++ks) {
        int frag = (chunk * 8 + m) * 4 + ks;
        f16x8 wh = *(const f16x8*)(W1img + frag * 512 + lane * 8);
        f16x8 wl = *(const f16x8*)(W1img + 65536 + frag * 512 + lane * 8);
        t4 = __builtin_amdgcn_mfma_f32_16x16x32_f16(wh, bfh[ks], t4, 0, 0, 0);
        t4 = __builtin_amdgcn_mfma_f32_16x16x32_f16(wl, bfh[ks], t4, 0, 0, 0);
        t4 = __builtin_amdgcn_mfma_f32_16x16x32_f16(wh, bfl[ks], t4, 0, 0, 0);
      }
      // t4[r] = h_pre[row=l15][col = chunk*128 + m*16 + l4*4 + r]
      float4 bv = *(const float4*)(b1 + chunk * 128 + m * 16 + l4 * 4);
      float4 g;
      g.x = gelu_f(t4[0] + bv.x);
      g.y = gelu_f(t4[1] + bv.y);
      g.z = gelu_f(t4[2] + bv.z);
      g.w = gelu_f(t4[3] + bv.w);
      // wave-local transpose staging: h row l15, within-chunk col m*16+l4*4
      *(float4*)(scr + l15 * RSTRIDE + m * 64 + l4 * 16) = g;
    }
    // ---- GEMM2: zacc[n] += h[16][128] @ W2[chunk] ----
#pragma unroll
    for (int ks = 0; ks < 4; ++ks) {
      const char* hb = scr + l15 * RSTRIDE + ks * 128 + l4 * 32;
      float4 h0 = *(const float4*)(hb);
      float4 h1 = *(const float4*)(hb + 16);
      f16x8 ah, al;
      split8(h0, h1, ah, al);
#pragma unroll
      for (int n = 0; n < 8; ++n) {
        int frag = (chunk * 8 + n) * 4 + ks;
        f16x8 bh = *(const f16x8*)(W2img + frag * 512 + lane * 8);
        f16x8 bl = *(const f16x8*)(W2img + 65536 + frag * 512 + lane * 8);
        zacc[n] = __builtin_amdgcn_mfma_f32_16x16x32_f16(ah, bh, zacc[n], 0, 0, 0);
        zacc[n] = __builtin_amdgcn_mfma_f32_16x16x32_f16(al, bh, zacc[n], 0, 0, 0);
        zacc[n] = __builtin_amdgcn_mfma_f32_16x16x32_f16(ah, bl, zacc[n], 0, 0, 0);
      }
    }
  }
}

// In-register LN over the wave's 16 rows (C/D layout). Row stats via 16-lane
// (same-l4) shuffle reduce; no LDS, no barrier.
#define ROW_LN_STATS(ZACC, MMV, RSV)                                   \
  float MMV[4], RSV[4];                                                \
  _Pragma("unroll") for (int r = 0; r < 4; ++r) {                      \
    float s = 0.f, q = 0.f;                                            \
    _Pragma("unroll") for (int n = 0; n < 8; ++n) {                    \
      float v = ZACC[n][r];                                            \
      s += v;                                                          \
      q += v * v;                                                      \
    }                                                                  \
    _Pragma("unroll") for (int m = 8; m >= 1; m >>= 1) {               \
      s += __shfl_xor(s, m, 64);                                       \
      q += __shfl_xor(q, m, 64);                                       \
    }                                                                  \
    float mm = s * (1.f / 128.f);                                      \
    float var = q * (1.f / 128.f) - mm * mm;                           \
    MMV[r] = mm;                                                       \
    RSV[r] = rsqrtf(var + 1e-5f);                                      \
  }

__global__ __launch_bounds__(256, 2) void tsal_kernel(
    const float* __restrict__ x,
    const float* __restrict__ bo_time, const float* __restrict__ bo_recv,
    const float* __restrict__ g1, const float* __restrict__ be1,
    const float* __restrict__ g2, const float* __restrict__ be2,
    const float* __restrict__ g3, const float* __restrict__ be3,
    const float* __restrict__ g4, const float* __restrict__ be4,
    const float* __restrict__ b1a, const float* __restrict__ b2a,
    const float* __restrict__ b1b, const float* __restrict__ b2b,
    float* __restrict__ out) {
  __shared__ __align__(16) char smem[33792];  // 4 waves x 16 x 528 B

  const int tid = threadIdx.x;
  const int lane = tid & 63;
  const int wv = tid >> 6;
  const int l15 = lane & 15, l4 = lane >> 4;
  char* scr = smem + wv * 8448;
  const int R0 = blockIdx.x * 64 + wv * 16;  // this wave's 16 rows

  // ---------------- Phase 0: LN1(x + bo_time) -> f32 scratch ----------------
  // 2 rows/iter: lanes 0-31 row rl, lanes 32-63 row rl+1. Wave-local.
#pragma unroll
  for (int it = 0; it < 8; ++it) {
    int rl = it * 2 + (lane >> 5);
    int c0 = (lane & 31) * 4;
    float4 xv = *(const float4*)(x + (size_t)(R0 + rl) * 128 + c0);
    float4 bt = *(const float4*)(bo_time + c0);
    float vx = xv.x + bt.x, vy = xv.y + bt.y, vz = xv.z + bt.z, vw = xv.w + bt.w;
    float s = vx + vy + vz + vw;
    float q = vx * vx + vy * vy + vz * vz + vw * vw;
#pragma unroll
    for (int m = 16; m >= 1; m >>= 1) {
      s += __shfl_xor(s, m, 64);
      q += __shfl_xor(q, m, 64);
    }
    float mm = s * (1.f / 128.f);
    float rs = rsqrtf(q * (1.f / 128.f) - mm * mm + 1e-5f);
    float4 gv = *(const float4*)(g1 + c0);
    float4 bv = *(const float4*)(be1 + c0);
    float4 w;
    w.x = (vx - mm) * rs * gv.x + bv.x;
    w.y = (vy - mm) * rs * gv.y + bv.y;
    w.z = (vz - mm) * rs * gv.z + bv.z;
    w.w = (vw - mm) * rs * gv.w + bv.w;
    *(float4*)(scr + rl * RSTRIDE + c0 * 4) = w;
  }

  // ---- activation B-frags of w^T (held in regs all of stage A) ----
  // bfh[ks] elem j = w[l15][ks*32 + l4*8 + j]
  f16x8 bfh[4], bfl[4];
#pragma unroll
  for (int ks = 0; ks < 4; ++ks) {
    const char* wb = scr + l15 * RSTRIDE + ks * 128 + l4 * 32;
    float4 a0 = *(const float4*)(wb);
    float4 a1 = *(const float4*)(wb + 16);
    split8(a0, a1, bfh[ks], bfl[ks]);
  }
  // ---- residual w into zacc (C/D layout scalar reads, exact f32) ----
  f32x4 zacc[8];
#pragma unroll
  for (int n = 0; n < 8; ++n)
#pragma unroll
    for (int r = 0; r < 4; ++r)
      zacc[n][r] = *(const float*)(scr + (l4 * 4 + r) * RSTRIDE +
                                   (n * 16 + l15) * 4);

  // ---------------- Stage A: z_pre = w + MLP1(w) ----------------
  mlp_stage(scr, bfh, bfl, zacc, g_wimg, g_wimg + 131072, b1a, lane, l15, l4);

  // + b2a; LN2; + bo_recv; LN3 -> y (all in-register)
  float b2v[8], g2v[8], be2v[8], brv[8], g3v[8], be3v[8];
#pragma unroll
  for (int n = 0; n < 8; ++n) {
    int col = n * 16 + l15;
    b2v[n] = b2a[col];
    g2v[n] = g2[col];
    be2v[n] = be2[col];
    brv[n] = bo_recv[col];
    g3v[n] = g3[col];
    be3v[n] = be3[col];
  }
#pragma unroll
  for (int n = 0; n < 8; ++n)
#pragma unroll
    for (int r = 0; r < 4; ++r) zacc[n][r] += b2v[n];
  {
    ROW_LN_STATS(zacc, mm2, rs2)
#pragma unroll
    for (int n = 0; n < 8; ++n)
#pragma unroll
      for (int r = 0; r < 4; ++r)
        zacc[n][r] = (zacc[n][r] - mm2[r]) * rs2[r] * g2v[n] + be2v[n] + brv[n];
  }
  {
    ROW_LN_STATS(zacc, mm3, rs3)
#pragma unroll
    for (int n = 0; n < 8; ++n)
#pragma unroll
      for (int r = 0; r < 4; ++r)
        zacc[n][r] = (zacc[n][r] - mm3[r]) * rs3[r] * g3v[n] + be3v[n];
  }
  // write y to scratch (C/D pattern), rebuild activation frags (y^T)
#pragma unroll
  for (int n = 0; n < 8; ++n)
#pragma unroll
    for (int r = 0; r < 4; ++r)
      *(float*)(scr + (l4 * 4 + r) * RSTRIDE + (n * 16 + l15) * 4) =
          zacc[n][r];
#pragma unroll
  for (int ks = 0; ks < 4; ++ks) {
    const char* yb = scr + l15 * RSTRIDE + ks * 128 + l4 * 32;
    float4 a0 = *(const float4*)(yb);
    float4 a1 = *(const float4*)(yb + 16);
    split8(a0, a1, bfh[ks], bfl[ks]);
  }

  // ---------------- Stage B: o_pre = y + MLP2(y) ----------------
  mlp_stage(scr, bfh, bfl, zacc, g_wimg + 262144, g_wimg + 393216, b1b, lane,
            l15, l4);

  // + b2b; LN4 -> out
  float b4v[8], g4v[8], be4v[8];
#pragma unroll
  for (int n = 0; n < 8; ++n) {
    int col = n * 16 + l15;
    b4v[n] = b2b[col];
    g4v[n] = g4[col];
    be4v[n] = be4[col];
  }
#pragma unroll
  for (int n = 0; n < 8; ++n)
#pragma unroll
    for (int r = 0; r < 4; ++r) zacc[n][r] += b4v[n];
  {
    ROW_LN_STATS(zacc, mm4, rs4)
#pragma unroll
    for (int n = 0; n < 8; ++n)
#pragma unroll
      for (int r = 0; r < 4; ++r) {
        float o = (zacc[n][r] - mm4[r]) * rs4[r] * g4v[n] + be4v[n];
        out[(size_t)(R0 + l4 * 4 + r) * 128 + n * 16 + l15] = o;
      }
  }
}

extern "C" void kernel_launch(void* const* d_in, const int* in_sizes, int n_in,
                              void* d_out, int out_size, void* d_ws, size_t ws_size,
                              hipStream_t stream) {
  const float* x = (const float*)d_in[0];
  // d_in[1] = router (dead), d_in[3] = bo_send (dead)
  const float* bo_time = (const float*)d_in[2];
  const float* bo_recv = (const float*)d_in[4];
  const float* g1 = (const float*)d_in[5];
  const float* be1 = (const float*)d_in[6];
  const float* g2 = (const float*)d_in[7];
  const float* be2 = (const float*)d_in[8];
  const float* g3 = (const float*)d_in[9];
  const float* be3 = (const float*)d_in[10];
  const float* g4 = (const float*)d_in[11];
  const float* be4 = (const float*)d_in[12];
  const float* b1a = (const float*)d_in[14];
  const float* b2a = (const float*)d_in[16];
  const float* b1b = (const float*)d_in[18];
  const float* b2b = (const float*)d_in[20];
  const float* W1a = (const float*)d_in[13];
  const float* W2a = (const float*)d_in[15];
  const float* W1b = (const float*)d_in[17];
  const float* W2b = (const float*)d_in[19];
  float* outp = (float*)d_out;

  int nrows = in_sizes[0] / 128;  // 131072
  prep_weights<<<1024, 256, 0, stream>>>(W1a, W2a, W1b, W2b);
  tsal_kernel<<<nrows / 64, 256, 0, stream>>>(
      x, bo_time, bo_recv, g1, be1, g2, be2, g3, be3, g4, be4,
      b1a, b2a, b1b, b2b, outp);
}